// Round 1
// baseline (335.232 us; speedup 1.0000x reference)
//
#include <hip/hip_runtime.h>
#include <math.h>

// Problem constants (from reference setup_inputs)
#define FDIM 1024
#define EDIM 64
#define BTOT 16384
#define NFLD 32

#define TILE 64       // P tile side
#define NT (FDIM / TILE)          // 16 tiles per dim
#define NPAIR (NT * (NT + 1) / 2) // 136 upper-tri tile pairs
#define BCHUNK 1024   // batch rows per block
#define KB 32         // staged batch rows per LDS stage

// ---------------------------------------------------------------------------
// Kernel A: W[i,j] = (j>i) ? sum_e vs[fields[j],i,e] * vs[fields[i],j,e] : 0
// ---------------------------------------------------------------------------
__global__ __launch_bounds__(256) void compute_W(
    const float* __restrict__ vs, const int* __restrict__ fields,
    float* __restrict__ W) {
  const int j = blockIdx.x * 16 + threadIdx.x;
  const int i = blockIdx.y * 16 + threadIdx.y;
  float acc = 0.f;
  if (j > i) {
    const float4* pa =
        (const float4*)(vs + ((size_t)fields[j] * FDIM + i) * EDIM);
    const float4* pb =
        (const float4*)(vs + ((size_t)fields[i] * FDIM + j) * EDIM);
#pragma unroll
    for (int e4 = 0; e4 < EDIM / 4; ++e4) {
      float4 a = pa[e4];
      float4 b = pb[e4];
      acc += a.x * b.x + a.y * b.y + a.z * b.z + a.w * b.w;
    }
  }
  W[(size_t)i * FDIM + j] = acc;
}

// ---------------------------------------------------------------------------
// Kernel B: for tile pair (ti,tj), b-chunk: P_tile = X[:,ti]^T X[:,tj] over the
// chunk, then partial += sum P_tile .* W_tile ; atomicAdd into s_out.
// ---------------------------------------------------------------------------
__global__ __launch_bounds__(256) void gram_dot(
    const float* __restrict__ X, const float* __restrict__ W,
    float* __restrict__ s_out) {
  // decode upper-tri tile pair
  int p = blockIdx.x;
  int ti = 0, rem = NT;
  while (p >= rem) { p -= rem; ++ti; --rem; }
  const int tj = ti + p;
  const int i0 = ti * TILE;
  const int j0 = tj * TILE;
  const int b0 = blockIdx.y * BCHUNK;

  __shared__ __align__(16) float Xi[KB][TILE];
  __shared__ __align__(16) float Xj[KB][TILE];

  const int t = threadIdx.x;
  const int tx = t & 15;   // col group (j)
  const int ty = t >> 4;   // row group (i)

  float acc[4][4];
#pragma unroll
  for (int r = 0; r < 4; ++r)
#pragma unroll
    for (int c = 0; c < 4; ++c) acc[r][c] = 0.f;

  for (int bb = 0; bb < BCHUNK; bb += KB) {
    __syncthreads();
    // stage KB x TILE for both column groups: 512 float4 per buffer, 256 thr
#pragma unroll
    for (int half = 0; half < 2; ++half) {
      int idx = t + half * 256;      // 0..511
      int kb = idx >> 4;             // row within stage
      int c4 = idx & 15;             // float4 col
      const size_t gr = (size_t)(b0 + bb + kb) * FDIM;
      float4 vi = *(const float4*)(X + gr + i0 + c4 * 4);
      float4 vj = *(const float4*)(X + gr + j0 + c4 * 4);
      *(float4*)&Xi[kb][c4 * 4] = vi;
      *(float4*)&Xj[kb][c4 * 4] = vj;
    }
    __syncthreads();

#pragma unroll
    for (int kb = 0; kb < KB; ++kb) {
      float4 a4 = *(const float4*)&Xi[kb][ty * 4];
      float4 b4 = *(const float4*)&Xj[kb][tx * 4];
      float a[4] = {a4.x, a4.y, a4.z, a4.w};
      float b[4] = {b4.x, b4.y, b4.z, b4.w};
#pragma unroll
      for (int r = 0; r < 4; ++r)
#pragma unroll
        for (int c = 0; c < 4; ++c) acc[r][c] += a[r] * b[c];
    }
  }

  // dot with W (W already zero for j<=i, so diagonal tiles self-mask)
  float part = 0.f;
#pragma unroll
  for (int r = 0; r < 4; ++r) {
    const int gi = i0 + ty * 4 + r;
#pragma unroll
    for (int c = 0; c < 4; ++c) {
      const int gj = j0 + tx * 4 + c;
      part += acc[r][c] * W[(size_t)gi * FDIM + gj];
    }
  }

  // block reduce
  __shared__ float red[256];
  __syncthreads();
  red[t] = part;
  __syncthreads();
  for (int off = 128; off > 0; off >>= 1) {
    if (t < off) red[t] += red[t + off];
    __syncthreads();
  }
  if (t == 0) atomicAdd(s_out, red[0]);
}

// ---------------------------------------------------------------------------
// Kernel C: out[b] = sigmoid(X[b,:].w + bias + s)
// ---------------------------------------------------------------------------
__global__ __launch_bounds__(256) void linear_out(
    const float* __restrict__ X, const float* __restrict__ w,
    const float* __restrict__ bias, const float* __restrict__ s,
    float* __restrict__ out) {
  const int lane = threadIdx.x & 63;
  const int wave = threadIdx.x >> 6;
  const int row = blockIdx.x * 4 + wave;

  const float4* xr = (const float4*)(X + (size_t)row * FDIM);
  const float4* wr = (const float4*)w;
  float acc = 0.f;
#pragma unroll
  for (int k = 0; k < 4; ++k) {
    int c = lane + 64 * k;
    float4 a = xr[c];
    float4 b = wr[c];
    acc += a.x * b.x + a.y * b.y + a.z * b.z + a.w * b.w;
  }
#pragma unroll
  for (int off = 32; off > 0; off >>= 1) acc += __shfl_down(acc, off, 64);

  if (lane == 0) {
    float z = acc + bias[0] + s[0];
    out[row] = 1.f / (1.f + expf(-z));
  }
}

// ---------------------------------------------------------------------------
extern "C" void kernel_launch(void* const* d_in, const int* in_sizes, int n_in,
                              void* d_out, int out_size, void* d_ws,
                              size_t ws_size, hipStream_t stream) {
  const float* X = (const float*)d_in[0];       // [B, F]
  const int* fields = (const int*)d_in[1];      // [F]
  const float* w_weight = (const float*)d_in[2];// [1, F]
  const float* w_bias = (const float*)d_in[3];  // [1]
  const float* vs = (const float*)d_in[4];      // [NF, F, E]
  float* out = (float*)d_out;                   // [B, 1]

  float* s_acc = (float*)d_ws;                  // scalar accumulator
  float* W = (float*)d_ws + 256;                // [F, F] weights (4 MB)

  hipMemsetAsync(d_ws, 0, 4, stream);

  compute_W<<<dim3(FDIM / 16, FDIM / 16), dim3(16, 16), 0, stream>>>(vs, fields,
                                                                     W);
  gram_dot<<<dim3(NPAIR, BTOT / BCHUNK), 256, 0, stream>>>(X, W, s_acc);
  linear_out<<<BTOT / 4, 256, 0, stream>>>(X, w_weight, w_bias, s_acc, out);
}

// Round 2
// 120.424 us; speedup vs baseline: 2.7838x; 2.7838x over previous
//
#include <hip/hip_runtime.h>
#include <hip/hip_fp16.h>
#include <math.h>
#include <stdint.h>

#define FDIM 1024
#define BTOT 16384
#define EDIM 64
#define NFLD 32

typedef _Float16 half8 __attribute__((ext_vector_type(8)));
typedef float f32x4 __attribute__((ext_vector_type(4)));

// XOR swizzle of the low-3 column bits by the next-3 bits; applied to the
// GLOBAL chunk layout (written by transpose_conv) AND the LDS read addressing
// in gram_mfma (both-sides-or-neither rule, since global_load_lds writes the
// LDS destination linearly).
__device__ __forceinline__ int swz(int c){ return (c & ~7) | ((c ^ (c >> 3)) & 7); }

__device__ __forceinline__ uint32_t pkh(float a, float b){
  _Float16 lo = (_Float16)a, hi = (_Float16)b;
  uint16_t ulo = __builtin_bit_cast(uint16_t, lo);
  uint16_t uhi = __builtin_bit_cast(uint16_t, hi);
  return ((uint32_t)uhi << 16) | (uint32_t)ulo;
}

__device__ __forceinline__ void gload16(const void* g, void* l){
  __builtin_amdgcn_global_load_lds((const __attribute__((address_space(1))) void*)g,
                                   (__attribute__((address_space(3))) void*)l,
                                   16, 0, 0);
}

// ---------------------------------------------------------------------------
// prep: bucket feature indices by field. grp[33] offsets, perm[1024] members.
// ---------------------------------------------------------------------------
__global__ void prep_groups(const int* __restrict__ fields, int* __restrict__ grp,
                            int* __restrict__ perm){
  __shared__ int cnt[NFLD];
  __shared__ int pos[NFLD];
  const int t = threadIdx.x;
  if (t < NFLD) cnt[t] = 0;
  __syncthreads();
  const int f = fields[t];
  atomicAdd(&cnt[f], 1);
  __syncthreads();
  if (t == 0){
    int s = 0;
    for (int i = 0; i < NFLD; ++i){ grp[i] = s; pos[i] = s; s += cnt[i]; }
    grp[NFLD] = s;
  }
  __syncthreads();
  const int p = atomicAdd(&pos[f], 1);
  perm[p] = t;
}

// ---------------------------------------------------------------------------
// W2: per field pair (a,b): for i in group(a), j in group(b):
//   W[i][j] = (j>i) ? sum_e vs[b][i][e]*vs[a][j][e] : 0
// Groups partition [0,1024) so every W entry is written exactly once.
// ---------------------------------------------------------------------------
__global__ __launch_bounds__(256) void compute_W2(
    const float* __restrict__ vs, const int* __restrict__ grp,
    const int* __restrict__ perm, float* __restrict__ W){
  const int a = blockIdx.y, b = blockIdx.x;
  const int oa = grp[a], na = grp[a + 1] - oa;
  const int ob = grp[b], nb = grp[b + 1] - ob;
  if (na == 0 || nb == 0) return;
  __shared__ float Si[64][68];  // vs[b][Ga rows]  (+4 pad: bank spread)
  __shared__ float Sj[64][68];  // vs[a][Gb rows]
  __shared__ int gI[64], gJ[64];
  const int t = threadIdx.x;
  for (int ia0 = 0; ia0 < na; ia0 += 64){
    const int nac = min(64, na - ia0);
    for (int jb0 = 0; jb0 < nb; jb0 += 64){
      const int nbc = min(64, nb - jb0);
      __syncthreads();
      if (t < 64){
        gI[t] = (t < nac) ? perm[oa + ia0 + t] : 0;
        gJ[t] = (t < nbc) ? perm[ob + jb0 + t] : 0;
      }
      __syncthreads();
#pragma unroll
      for (int rep = 0; rep < 4; ++rep){
        const int lin = rep * 256 + t;
        const int r = lin >> 4, e4 = (lin & 15) * 4;
        if (r < nac)
          *(float4*)&Si[r][e4] = *(const float4*)(vs + ((size_t)b * FDIM + gI[r]) * EDIM + e4);
        if (r < nbc)
          *(float4*)&Sj[r][e4] = *(const float4*)(vs + ((size_t)a * FDIM + gJ[r]) * EDIM + e4);
      }
      __syncthreads();
      const int jr = t & 63;
      for (int ko = 0; ko * 4 < nac; ++ko){
        const int ir = ko * 4 + (t >> 6);
        if (ir < nac && jr < nbc){
          float dot = 0.f;
#pragma unroll
          for (int e4 = 0; e4 < EDIM; e4 += 4){
            const float4 x = *(const float4*)&Si[ir][e4];
            const float4 y = *(const float4*)&Sj[jr][e4];
            dot += x.x * y.x + x.y * y.y + x.z * y.z + x.w * y.w;
          }
          const int gi = gI[ir], gj = gJ[jr];
          W[(size_t)gi * FDIM + gj] = (gj > gi) ? dot : 0.f;
        }
      }
    }
  }
}

// ---------------------------------------------------------------------------
// transpose_conv: X [16384][1024] f32 -> Xbt fp16 chunk layout:
//   chunk index = (panel*2048 + k/8)*128 + swz(col within panel), 16B = 8 k's
// of one column. Also fuses the linear term: lin[k] += dot(X[k, panel], w).
// ---------------------------------------------------------------------------
__global__ __launch_bounds__(256) void transpose_conv(
    const float* __restrict__ X, const float* __restrict__ w,
    uint4* __restrict__ Xbt, float* __restrict__ lin){
  const int p  = blockIdx.x & 7;
  const int kb = blockIdx.x >> 3;
  const int t  = threadIdx.x;
  const int q  = t & 31;        // col quad within panel
  const int ro = t >> 5;        // row oct 0..7
  const int k0 = kb * 64 + ro * 8;
  const int c0 = p * 128 + q * 4;

  float xs[8][4];
#pragma unroll
  for (int r = 0; r < 8; ++r){
    const float4 v = *(const float4*)(X + (size_t)(k0 + r) * FDIM + c0);
    xs[r][0] = v.x; xs[r][1] = v.y; xs[r][2] = v.z; xs[r][3] = v.w;
  }

  // fused linear partials: reduce over the 32 col-quad lanes of this row oct
  const float4 w4 = *(const float4*)(w + c0);
#pragma unroll
  for (int r = 0; r < 8; ++r){
    float lp = xs[r][0] * w4.x + xs[r][1] * w4.y + xs[r][2] * w4.z + xs[r][3] * w4.w;
#pragma unroll
    for (int off = 16; off; off >>= 1) lp += __shfl_xor(lp, off, 64);
    if (q == 0) atomicAdd(&lin[k0 + r], lp);
  }

  const int og = kb * 8 + ro;  // global k-oct
  uint4* dst = Xbt + ((size_t)p * 2048 + og) * 128;
#pragma unroll
  for (int i = 0; i < 4; ++i){
    uint4 ch;
    ch.x = pkh(xs[0][i], xs[1][i]);
    ch.y = pkh(xs[2][i], xs[3][i]);
    ch.z = pkh(xs[4][i], xs[5][i]);
    ch.w = pkh(xs[6][i], xs[7][i]);
    dst[swz(q * 4 + i)] = ch;
  }
}

// ---------------------------------------------------------------------------
// gram_mfma: upper-tri 128x128 tile pairs (36) x 16 k-splits of 1024 rows.
// P-tile = Xi^T Xj via mfma_f32_16x16x32_f16, epilogue dots with W tile,
// block-reduce, atomicAdd scalar. m97 structure: global_load_lds width 16,
// single 32KB LDS buffer, 2 barriers per 64-row stage.
// ---------------------------------------------------------------------------
__global__ __launch_bounds__(256) void gram_mfma(
    const uint4* __restrict__ Xbt, const float* __restrict__ W,
    float* __restrict__ s_out){
  int pp = blockIdx.x, ti = 0, rem = 8;
  while (pp >= rem){ pp -= rem; ++ti; --rem; }
  const int tj = ti + pp;
  const int ko0 = blockIdx.y * 128;  // 128 octs = 1024 batch rows per block

  __shared__ uint4 lds[2048];        // [0..1023]=A slice, [1024..2047]=B slice
  const int t = threadIdx.x, w = t >> 6, lane = t & 63;
  const int m0 = (w >> 1) * 64, n0 = (w & 1) * 64;
  const int orow = lane >> 4, rl = lane & 15;

  const uint4* gA = Xbt + ((size_t)ti * 2048 + ko0) * 128;
  const uint4* gB = Xbt + ((size_t)tj * 2048 + ko0) * 128;

  f32x4 acc[4][4];
#pragma unroll
  for (int i = 0; i < 4; ++i)
#pragma unroll
    for (int j = 0; j < 4; ++j) acc[i][j] = {0.f, 0.f, 0.f, 0.f};

  int swA[4], swB[4];
#pragma unroll
  for (int mb = 0; mb < 4; ++mb) swA[mb] = swz(m0 + mb * 16 + rl);
#pragma unroll
  for (int nb = 0; nb < 4; ++nb) swB[nb] = 1024 + swz(n0 + nb * 16 + rl);

  for (int st = 0; st < 16; ++st){   // 16 stages x 8 octs = 128 octs
    __syncthreads();
#pragma unroll
    for (int n = 0; n < 8; ++n){
      const int cb = w * 8 + n;      // chunk-block 0..31 (64 chunks each)
      const int cbl = cb & 15;
      const uint4* src = ((cb < 16) ? gA : gB) + (size_t)st * 1024 + (size_t)cbl * 64 + lane;
      gload16(src, lds + (cb >> 4) * 1024 + cbl * 64);
    }
    __syncthreads();
#pragma unroll
    for (int s2 = 0; s2 < 2; ++s2){
      const int ob = (s2 * 4 + orow) * 128;
      half8 af[4], bf[4];
#pragma unroll
      for (int mb = 0; mb < 4; ++mb) af[mb] = __builtin_bit_cast(half8, lds[ob + swA[mb]]);
#pragma unroll
      for (int nb = 0; nb < 4; ++nb) bf[nb] = __builtin_bit_cast(half8, lds[ob + swB[nb]]);
#pragma unroll
      for (int mb = 0; mb < 4; ++mb)
#pragma unroll
        for (int nb = 0; nb < 4; ++nb)
          acc[mb][nb] = __builtin_amdgcn_mfma_f32_16x16x32_f16(af[mb], bf[nb], acc[mb][nb], 0, 0, 0);
    }
  }

  // epilogue: dot with W tile (W is 0 for j<=i, masking diagonal tiles)
  const int i0 = ti * 128 + m0, j0 = tj * 128 + n0;
  float part = 0.f;
#pragma unroll
  for (int mb = 0; mb < 4; ++mb){
#pragma unroll
    for (int r = 0; r < 4; ++r){
      const int gi = i0 + mb * 16 + orow * 4 + r;
      const float* Wr = W + (size_t)gi * FDIM + j0 + rl;
#pragma unroll
      for (int nb = 0; nb < 4; ++nb)
        part += acc[mb][nb][r] * Wr[nb * 16];
    }
  }
#pragma unroll
  for (int off = 32; off; off >>= 1) part += __shfl_xor(part, off, 64);
  if (lane == 0) atomicAdd(s_out, part);
}

// ---------------------------------------------------------------------------
__global__ void final_out(const float* __restrict__ lin, const float* __restrict__ wb,
                          const float* __restrict__ s, float* __restrict__ out){
  const int i = blockIdx.x * 256 + threadIdx.x;
  const float z = lin[i] + wb[0] + s[0];
  out[i] = 1.f / (1.f + expf(-z));
}

// ---------------------------------------------------------------------------
extern "C" void kernel_launch(void* const* d_in, const int* in_sizes, int n_in,
                              void* d_out, int out_size, void* d_ws,
                              size_t ws_size, hipStream_t stream) {
  const float* X      = (const float*)d_in[0];  // [B, F]
  const int* fields   = (const int*)d_in[1];    // [F]
  const float* ww     = (const float*)d_in[2];  // [1, F]
  const float* wbias  = (const float*)d_in[3];  // [1]
  const float* vs     = (const float*)d_in[4];  // [NF, F, E]
  float* out          = (float*)d_out;          // [B, 1]

  char* ws = (char*)d_ws;
  float* s_acc = (float*)ws;                       // 4 B scalar
  float* lin   = (float*)(ws + 1024);              // 64 KB
  int* grp     = (int*)(ws + 1024 + 65536);        // 33 ints
  int* perm    = (int*)(ws + 1024 + 65536 + 256);  // 4 KB
  float* W     = (float*)(ws + (size_t)(4 << 20)); // 4 MB at 4 MB offset
  uint4* Xbt   = (uint4*)(ws + (size_t)(8 << 20)); // 32 MB at 8 MB offset

  hipMemsetAsync(ws, 0, 1024 + 65536, stream);     // s_acc + lin

  prep_groups<<<1, 1024, 0, stream>>>(fields, grp, perm);
  compute_W2<<<dim3(32, 32), 256, 0, stream>>>(vs, grp, perm, W);
  transpose_conv<<<2048, 256, 0, stream>>>(X, ww, Xbt, lin);
  gram_mfma<<<dim3(36, 16), 256, 0, stream>>>(Xbt, W, s_acc);
  final_out<<<64, 256, 0, stream>>>(lin, wbias, s_acc, out);
}